// Round 8
// baseline (514.248 us; speedup 1.0000x reference)
//
#include <hip/hip_runtime.h>
#include <float.h>

#define NB 32
#define NBCE 32
#define L 128
#define NT 256                     /* 4 waves per block: test barrier-convoy scaling */
#define R 132                      /* row stride of mirror-square (R = 4 mod 32) */
#define PAD 40                     /* tail pad: masked overreads stay in-bounds */
#define LOGMIN -87.49823f          /* ln(1e-38) */

// ---- mask dtype runtime detection (element [0] is guaranteed true: lens >= 64) ----
__device__ __forceinline__ int mask_mode(const void* p) {
    unsigned int v = ((const unsigned int*)p)[0];
    if (v == 1u) return 1;            // int32 0/1 storage
    if (v == 0x3F800000u) return 2;   // float32 storage
    return 0;                         // byte storage
}
__device__ __forceinline__ bool mask_at(const void* p, int mode, int idx) {
    if (mode == 1) return ((const int*)p)[idx] != 0;
    if (mode == 2) return ((const float*)p)[idx] != 0.0f;
    return ((const unsigned char*)p)[idx] != 0;
}

__device__ __forceinline__ float lse2(float a, float b) {
    return fmaxf(a, b) + log1pf(__expf(-fabsf(a - b)));
}

// ---- DPP butterfly reduce within aligned subgroups of 8 lanes ----
template<int C>
__device__ __forceinline__ float dppf(float x) {
    return __int_as_float(__builtin_amdgcn_mov_dpp(__float_as_int(x), C, 0xF, 0xF, true));
}
__device__ __forceinline__ float bfly_max8(float x) {
    x = fmaxf(x, dppf<0xB1>(x));   // lane^1
    x = fmaxf(x, dppf<0x4E>(x));   // lane^2
    x = fmaxf(x, dppf<0x141>(x));  // row_half_mirror: ^7 within 8
    return x;
}
__device__ __forceinline__ float bfly_add8(float x) {
    x += dppf<0xB1>(x);
    x += dppf<0x4E>(x);
    x += dppf<0x141>(x);
    return x;
}

// load terms t = sub + kk*8 from two contiguous LDS streams; dynamic trip count.
// v[kk] left -FLT_MAX-safe; mloc updated with running max.  (R0-proven)
template<int NUMAX>
__device__ __forceinline__ void load_terms(float* v, int sub, int nterm,
                                           const float* p1, const float* p2, float& mloc) {
    p1 += sub; p2 += sub;
#pragma unroll
    for (int kk = 0; kk < NUMAX; kk += 2) {
        if (kk * 8 >= nterm) break;
        const int o0 = kk * 8, o1 = o0 + 8;
        float a0 = p1[o0] + p2[o0];
        float a1 = p1[o1] + p2[o1];
        a0 = (sub + o0 < nterm) ? a0 : -FLT_MAX;
        a1 = (sub + o1 < nterm) ? a1 : -FLT_MAX;
        v[kk] = a0; v[kk + 1] = a1;
        mloc = fmaxf(mloc, fmaxf(a0, a1));
    }
}
template<int NUMAX>
__device__ __forceinline__ void sum_exp8(const float* v, int nterm, float M, float& s) {
#pragma unroll
    for (int kk = 0; kk < NUMAX; kk += 2) {
        if (kk * 8 >= nterm) break;
        s += __expf(v[kk] - M) + __expf(v[kk + 1] - M);
    }
}

// ================= fused kernel: blocks [0,NB) = per-batch DP; [NB,NB+NBCE) = BCE =================
__global__ __launch_bounds__(NT, 1) void tree_dp_kernel(
    const float* __restrict__ logits,   // [B,L,L,2]
    const int*   __restrict__ spans_ind,// [B,L,L]
    const void*  __restrict__ maskspan, // [B,L,L] bool
    const float* __restrict__ ph, const float* __restrict__ pt,
    const int* __restrict__ ph_ind, const int* __restrict__ pt_ind,
    const void* __restrict__ maskarc,
    double*      __restrict__ ws)
{
    const int tid = threadIdx.x;

    // ---------------- BCE blocks (no LDS use) ----------------
    if (blockIdx.x >= NB) {
        const int mode = mask_mode(maskarc);
        const int tot = NB * L * L;
        double sph = 0.0, spt = 0.0, cnt = 0.0;
        for (int idx = (blockIdx.x - NB) * NT + tid; idx < tot; idx += NBCE * NT) {
            if (mask_at(maskarc, mode, idx)) {
                float x = ph[idx]; float y = (float)ph_ind[idx];
                sph += (double)(fmaxf(x, 0.0f) - x * y + log1pf(__expf(-fabsf(x))));
                x = pt[idx]; y = (float)pt_ind[idx];
                spt += (double)(fmaxf(x, 0.0f) - x * y + log1pf(__expf(-fabsf(x))));
                cnt += 1.0;
            }
        }
        for (int off = 32; off > 0; off >>= 1) {
            sph += __shfl_down(sph, off);
            spt += __shfl_down(spt, off);
            cnt += __shfl_down(cnt, off);
        }
        if ((tid & 63) == 0) {
            atomicAdd(&ws[2], sph); atomicAdd(&ws[3], spt); atomicAdd(&ws[4], cnt);
        }
        return;
    }

    // ---------------- DP blocks ----------------
    // mirror-square: Am[i*R+j] == Am[j*R+i] == alpha[i,j] (i<=j). Same for Gm (gamma).
    // Untouched slots hold sc.
    __shared__ __align__(16) float Am[L * R + PAD];
    __shared__ __align__(16) float Gm[L * R + PAD];

    const int b = blockIdx.x;
    const int mbase = b * L * L;
    const int mode = mask_mode(maskspan);

    int pred = (tid < L) && mask_at(maskspan, mode, mbase + tid);
    const int n = __syncthreads_count(pred);

    const float* lg = logits + (size_t)b * L * L * 2;
    const int* si = spans_ind + mbase;

    // ---- init: sc into both mirror halves of Am and Gm ----
    for (int e = tid; e < L * L; e += NT) {
        int i = e >> 7, j = e & (L - 1);
        if (i <= j && j < n) {
            const float* p = lg + (size_t)e * 2;
            float v = lse2(p[0], p[1]);
            Am[i * R + j] = v; Am[j * R + i] = v;
            Gm[i * R + j] = v; Gm[j * R + i] = v;
        }
    }
    __syncthreads();

    const int sg = tid >> 3, sub = tid & 7;   // 32 subgroups of 8 lanes

    // ======== INSIDE: widths 1..n-1 ========
    // alpha[i,j] = sc[i,j] + LSE_t( alpha[i,i+t] + alpha[i+1+t,j] ), t in [0,w)
    // left stream: Am row i cols i.. (contig); right: Am row j (mirror) cols i+1.. (contig)
    for (int w = 1; w < n; ++w) {
        const int c = n - w;
#pragma unroll
        for (int q = 0; q < 4; ++q) {
            const int i = sg + (q << 5);
            if (i >= c) break;
            const int j = i + w;
            float v[16]; float mloc = -FLT_MAX;
            load_terms<16>(v, sub, w, &Am[i * R + i], &Am[j * R + i + 1], mloc);
            float M = bfly_max8(mloc);
            float s = 0.0f;
            sum_exp8<16>(v, w, M, s);
            float S = bfly_add8(s);
            if (sub == 0) {
                float val = Am[i * R + j] + M + __logf(S);  // slot holds sc
                Am[i * R + j] = val; Am[j * R + i] = val;
            }
        }
        __syncthreads();
    }

    const float logZ = Am[n - 1];   // alpha[0, n-1]

    // ======== OUTSIDE: widths n-2..1 ========
    // gamma[i,j] = sc[i,j] + LSE( k>j: gamma[i,k]+alpha[j+1,k] ; k<i: gamma[k,j]+alpha[k,i-1] )
    for (int w = n - 2; w >= 1; --w) {
        const int c = n - w;
#pragma unroll
        for (int q = 0; q < 4; ++q) {
            const int i = sg + (q << 5);
            if (i >= c) break;
            const int j = i + w;
            const int nt1 = n - 1 - j;
            float v1[16], v2[16]; float mloc = -FLT_MAX;
            load_terms<16>(v1, sub, nt1, &Gm[i * R + j + 1], &Am[(j + 1) * R + j + 1], mloc);
            load_terms<16>(v2, sub, i,   &Gm[j * R],         &Am[(i - 1) * R],         mloc);
            float M = bfly_max8(mloc);
            float s = 0.0f;
            sum_exp8<16>(v1, nt1, M, s);
            sum_exp8<16>(v2, i,   M, s);
            float S = bfly_add8(s);
            if (sub == 0) {
                float val = Gm[i * R + j] + M + __logf(S);  // slot holds sc
                Gm[i * R + j] = val; Gm[j * R + i] = val;
            }
        }
        __syncthreads();
    }

    // ---- fused w=0 outside (beta_ii) + diagonal loss ----
    double local = 0.0;
#pragma unroll
    for (int q = 0; q < 4; ++q) {
        const int i = sg + (q << 5);
        if (i >= n) break;
        const int nt1 = n - 1 - i;
        float v1[16], v2[16]; float mloc = -FLT_MAX;
        load_terms<16>(v1, sub, nt1, &Gm[i * R + i + 1], &Am[(i + 1) * R + i + 1], mloc);
        load_terms<16>(v2, sub, i,   &Gm[i * R],         &Am[(i - 1) * R],         mloc);
        float M = bfly_max8(mloc);
        float s = 0.0f;
        sum_exp8<16>(v1, nt1, M, s);
        sum_exp8<16>(v2, i,   M, s);
        float S = bfly_add8(s);
        if (sub == 0) {
            float beta_ii = M + __logf(S);
            const float* p = lg + ((size_t)i * L + i) * 2;
            int ind = si[i * L + i];
            float lc = (ind == 2) ? p[1] : p[0];
            // log marg = beta_ii - logZ + l_c  (alpha_ii == sc_ii cancels)
            local += (double)fmaxf(beta_ii - logZ + lc, LOGMIN);
        }
    }

    // ---- strict-upper loss ----
    for (int e = tid; e < L * L; e += NT) {
        int i = e >> 7, j = e & (L - 1);
        if (i < j && j < n) {
            const float* p = lg + (size_t)e * 2;
            float a = p[0], cc = p[1];
            float sc = lse2(a, cc);
            int ind = si[e];
            float lc = (ind == 2) ? cc : a;
            // log marg = alpha + (gamma - sc) - logZ + l_c - sc
            float logm = Am[i * R + j] + Gm[i * R + j] - logZ + lc - 2.0f * sc;
            local += (double)fmaxf(logm, LOGMIN);
        }
    }

    // wave reduce + one atomic per wave
    for (int off = 32; off > 0; off >>= 1)
        local += __shfl_down(local, off);
    if ((tid & 63) == 0) atomicAdd(&ws[0], local);
    if (tid == 0) atomicAdd(&ws[1], (double)n);
}

// ================= finalize =================
__global__ void finalize_kernel(const double* __restrict__ ws, float* __restrict__ out) {
    double loss_spans = -ws[0] / ws[1];
    double bce = (ws[2] + ws[3]) / ws[4];
    out[0] = (float)(0.5 * loss_spans + 0.5 * bce);
}

extern "C" void kernel_launch(void* const* d_in, const int* in_sizes, int n_in,
                              void* d_out, int out_size, void* d_ws, size_t ws_size,
                              hipStream_t stream) {
    (void)in_sizes; (void)n_in; (void)out_size; (void)ws_size;
    const float* span_logits = (const float*)d_in[0];
    const float* ph          = (const float*)d_in[1];
    const float* pt          = (const float*)d_in[2];
    /* d_in[3] = ph_arc: unused by reference */
    const int*   spans_ind   = (const int*)d_in[4];
    const int*   ph_ind      = (const int*)d_in[5];
    const int*   pt_ind      = (const int*)d_in[6];
    const void*  maskspan    = d_in[7];
    const void*  maskarc     = d_in[8];
    double* ws = (double*)d_ws;
    float* out = (float*)d_out;

    hipMemsetAsync(d_ws, 0, 5 * sizeof(double), stream);
    hipLaunchKernelGGL(tree_dp_kernel, dim3(NB + NBCE), dim3(NT), 0, stream,
                       span_logits, spans_ind, maskspan,
                       ph, pt, ph_ind, pt_ind, maskarc, ws);
    hipLaunchKernelGGL(finalize_kernel, dim3(1), dim3(1), 0, stream, ws, out);
}